// Round 2
// baseline (1190.216 us; speedup 1.0000x reference)
//
#include <hip/hip_runtime.h>

#define CC 64
#define HH 256
#define WW 256
#define HW (HH * WW)

typedef float v2f __attribute__((ext_vector_type(2)));

// Wcomb2[((i*64 + c)*9 + t)*64 + o] = sum_c2 Wfuse[o, i*64+c2] * Wd[i, c2, c, t]
__global__ void wcomb_kernel(const float* __restrict__ Wd,
                             const float* __restrict__ Wfuse,
                             float* __restrict__ Wcomb) {
    int idx = blockIdx.x * blockDim.x + threadIdx.x;
    if (idx >= 3 * 64 * 9 * 64) return;
    int o = idx & 63;
    int ct = idx >> 6;        // ((i*64 + c)*9 + t)
    int t = ct % 9;
    int c = (ct / 9) & 63;
    int i = ct / 9 / 64;
    const float* wf = Wfuse + o * 192 + i * 64;                    // c2 stride 1
    const float* wd = Wd + ((size_t)(i * 64) * 64 + c) * 9 + t;   // c2 stride 576
    float s = 0.f;
    for (int c2 = 0; c2 < 64; ++c2)
        s = fmaf(wf[c2], wd[(size_t)c2 * 576], s);
    Wcomb[idx] = s;
}

// One wave = 64 consecutive pixels of one row (lane = w). Block = 4 waves =
// one full image row. XCD-aware swizzle: blocks (8k+x) -> row x*64+k so each
// XCD's L2 holds a contiguous ~64-row band of x (~2.8 MB < 4 MB).
__launch_bounds__(256, 2)
__global__ void mspadc_main(const float* __restrict__ x,
                            const float* __restrict__ Woff,
                            const float* __restrict__ boff,
                            const float* __restrict__ Wcomb,
                            float* __restrict__ out) {
    const int tid = threadIdx.x;
    const int lane = tid & 63;
    const int wv = tid >> 6;
    const int row = ((blockIdx.x & 7) << 6) | (blockIdx.x >> 3);  // 0..511
    const int b = row >> 8;
    const int h = row & 255;
    const int w = (wv << 6) + lane;

    const float* xb = x + (size_t)b * CC * HW;

    // ---- Phase 1: offsets, packed in pairs (dy,dx): off2[i*9+k] ----
    v2f off2[27];
    const v2f* b2 = (const v2f*)boff;
#pragma unroll
    for (int n = 0; n < 27; ++n) off2[n] = b2[n];

    {
        const float* xc = xb;
        for (int c = 0; c < CC; ++c, xc += HW) {
            float xv[9];
#pragma unroll
            for (int t = 0; t < 9; ++t) {
                const int yy = h + (t / 3) - 1;
                const int xx = w + (t % 3) - 1;
                const bool v = (yy >= 0) && (yy < HH) && (xx >= 0) && (xx < WW);
                xv[t] = v ? xc[yy * WW + xx] : 0.f;
            }
            const float* wp = Woff + c * 9;   // + n*576 + t
#pragma unroll
            for (int n = 0; n < 27; ++n) {
                v2f a = off2[n];
#pragma unroll
                for (int t = 0; t < 9; ++t) {
                    v2f wt = { wp[(2 * n) * 576 + t], wp[(2 * n + 1) * 576 + t] };
                    v2f xt = { xv[t], xv[t] };
                    a = __builtin_elementwise_fma(wt, xt, a);
                }
                off2[n] = a;
            }
        }
    }

    // ---- Phase 2: per-dilation tap setup, channel loop with tap-inner ----
    v2f acc2[32];
#pragma unroll
    for (int o = 0; o < 32; ++o) acc2[o] = (v2f){0.f, 0.f};

    const float fh = (float)h, fw = (float)w;

#pragma unroll
    for (int i = 0; i < 3; ++i) {
        const int d = 1 << i;   // 1,2,4
        int base[9], xs1[9], ysW[9];
        float c00[9], c01[9], c10[9], c11[9];
#pragma unroll
        for (int t = 0; t < 9; ++t) {
            const float dy = off2[i * 9 + t].x;
            const float dx = off2[i * 9 + t].y;
            const float ys = fh + (float)((t / 3 - 1) * d) + dy;
            const float xs = fw + (float)((t % 3 - 1) * d) + dx;
            const float y0f = floorf(ys), x0f = floorf(xs);
            const float wy1 = ys - y0f, wx1 = xs - x0f;
            const float wy0 = 1.f - wy1, wx0 = 1.f - wx1;
            const float vy0 = (y0f >= 0.f && y0f <= 255.f) ? 1.f : 0.f;
            const float vy1 = (y0f >= -1.f && y0f <= 254.f) ? 1.f : 0.f;
            const float vx0 = (x0f >= 0.f && x0f <= 255.f) ? 1.f : 0.f;
            const float vx1 = (x0f >= -1.f && x0f <= 254.f) ? 1.f : 0.f;
            c00[t] = wy0 * wx0 * vy0 * vx0;
            c01[t] = wy0 * wx1 * vy0 * vx1;
            c10[t] = wy1 * wx0 * vy1 * vx0;
            c11[t] = wy1 * wx1 * vy1 * vx1;
            const int y0 = (int)fminf(fmaxf(y0f, 0.f), 255.f);
            const int y1 = (int)fminf(fmaxf(y0f + 1.f, 0.f), 255.f);
            const int x0 = (int)fminf(fmaxf(x0f, 0.f), 255.f);
            const int x1 = (int)fminf(fmaxf(x0f + 1.f, 0.f), 255.f);
            base[t] = y0 * WW + x0;
            xs1[t] = x1 - x0;          // 0 or 1
            ysW[t] = (y1 - y0) * WW;   // 0 or WW
        }

        const float* pc = xb;
        const float* wcb = Wcomb + (size_t)i * 64 * 9 * 64;
        for (int c = 0; c < CC; ++c, pc += HW) {
            float s[9];
#pragma unroll
            for (int t = 0; t < 9; ++t) {
                const int o00 = base[t];
                const int o01 = o00 + xs1[t];
                const int o10 = o00 + ysW[t];
                const int o11 = o10 + xs1[t];
                float sv = pc[o00] * c00[t];
                sv = fmaf(pc[o01], c01[t], sv);
                sv = fmaf(pc[o10], c10[t], sv);
                sv = fmaf(pc[o11], c11[t], sv);
                s[t] = sv;
            }
            const v2f* wc2 = (const v2f*)(wcb + (size_t)c * 9 * 64);
#pragma unroll
            for (int t = 0; t < 9; ++t) {
                const v2f sv2 = { s[t], s[t] };
                const v2f* w2 = wc2 + t * 32;
#pragma unroll
                for (int o = 0; o < 32; ++o)
                    acc2[o] = __builtin_elementwise_fma(w2[o], sv2, acc2[o]);
            }
        }
    }

    float* op = out + (size_t)b * CC * HW + (size_t)h * WW + w;
#pragma unroll
    for (int o = 0; o < 32; ++o) {
        op[(size_t)(2 * o) * HW] = acc2[o].x;
        op[(size_t)(2 * o + 1) * HW] = acc2[o].y;
    }
}

extern "C" void kernel_launch(void* const* d_in, const int* in_sizes, int n_in,
                              void* d_out, int out_size, void* d_ws, size_t ws_size,
                              hipStream_t stream) {
    const float* x     = (const float*)d_in[0];
    const float* Woff  = (const float*)d_in[1];
    const float* boff  = (const float*)d_in[2];
    const float* Wd    = (const float*)d_in[3];
    const float* Wfuse = (const float*)d_in[4];
    float* out = (float*)d_out;
    float* Wcomb = (float*)d_ws;   // 3*64*9*64 floats = 442,368 B

    wcomb_kernel<<<432, 256, 0, stream>>>(Wd, Wfuse, Wcomb);
    mspadc_main<<<512, 256, 0, stream>>>(x, Woff, boff, Wcomb, out);
}